// Round 6
// baseline (139.958 us; speedup 1.0000x reference)
//
#include <hip/hip_runtime.h>
#include <hip/hip_bf16.h>

#define M_TOT 32768
#define DDIM  1024
#define ODIM  768
#define LN_EPS 1e-5f

typedef __attribute__((__ext_vector_type__(8))) short bf16x8;
typedef __attribute__((__ext_vector_type__(4))) float f32x4;

__device__ __forceinline__ unsigned short f2bf(float f) {
  union { __hip_bfloat16 h; unsigned short u; } cv;
  cv.h = __float2bfloat16(f);
  return cv.u;
}

__device__ __forceinline__ float silu_f(float v) {
  return v / (1.f + __expf(-v));
}

__global__ void wconv_kernel(const float4* __restrict__ Wf, ushort4* __restrict__ Wb, int n4) {
  int i = blockIdx.x * blockDim.x + threadIdx.x;
  if (i >= n4) return;
  float4 v = Wf[i];
  ushort4 o;
  o.x = f2bf(v.x); o.y = f2bf(v.y); o.z = f2bf(v.z); o.w = f2bf(v.w);
  Wb[i] = o;
}

__device__ __forceinline__ void gload16(const void* g, void* l) {
  __builtin_amdgcn_global_load_lds(
      (const __attribute__((address_space(1))) unsigned int*)g,
      (__attribute__((address_space(3))) unsigned int*)l, 16, 0, 0);
}

#define VMW(n) asm volatile("s_waitcnt vmcnt(" #n ")" ::: "memory")

// ======= fused LN+SiLU+GEMM+rearrange, BM=64 x BN=768 (full N) =======
// 512 thr = 8 waves, 1M x 8N (wave C = 64 x 96). BK=32, ring-2 LDS.
// buf = A 64x64B (4 KB) + B 768x64B (48 KB) = 53248 B; x2 = 106496.
// lnw_s 4 KB @106496, lnb_s 4 KB @110592, stats 512 B @114688. Total 115200.
#define FBUF 53248
#define FABY 4096
#define LNW_OFF 106496
#define LNB_OFF 110592
#define STAT_OFF 114688

__global__ __launch_bounds__(512, 2)
void fusedln_gemm_kernel(const float* __restrict__ x,
                         const float* __restrict__ lnw,
                         const float* __restrict__ lnb,
                         const __hip_bfloat16* __restrict__ Wb,
                         const float* __restrict__ bias,
                         float* __restrict__ out)
{
  __shared__ char smem[115200];
  const int tid  = threadIdx.x;
  const int lane = tid & 63;
  const int w    = tid >> 6;
  const int m0   = blockIdx.x << 6;

  float* lnw_s = (float*)(smem + LNW_OFF);
  float* lnb_s = (float*)(smem + LNB_OFF);
  float* smean = (float*)(smem + STAT_OFF);
  float* srstd = smean + 64;

  // ---------- stats pass (8 thr/row) + LN param preload ----------
  {
    lnw_s[tid]       = lnw[tid];
    lnw_s[tid + 512] = lnw[tid + 512];
    lnb_s[tid]       = lnb[tid];
    lnb_s[tid + 512] = lnb[tid + 512];
    const int row = tid >> 3;
    const int sub = tid & 7;
    const float4* xr = (const float4*)(x + (size_t)(m0 + row) * DDIM);
    float s = 0.f, ss = 0.f;
#pragma unroll 8
    for (int j = 0; j < 32; ++j) {
      float4 v = xr[sub + (j << 3)];
      s  += v.x + v.y + v.z + v.w;
      ss += v.x * v.x + v.y * v.y + v.z * v.z + v.w * v.w;
    }
#pragma unroll
    for (int off = 1; off < 8; off <<= 1) {
      s  += __shfl_xor(s, off);
      ss += __shfl_xor(ss, off);
    }
    if (sub == 0) {
      float mean = s * (1.f / 1024.f);
      float var  = ss * (1.f / 1024.f) - mean * mean;
      smean[row] = mean;
      srstd[row] = rsqrtf(var + LN_EPS);
    }
  }
  __syncthreads();

  // ---------- A reg-staging setup (thread: row=tid>>3, 4 k-elems) ----------
  const int arow = tid >> 3;
  const int ak4  = tid & 7;
  const float aMean = smean[arow];
  const float aRstd = srstd[arow];
  const float* aSrc = x + (size_t)(m0 + arow) * DDIM + (ak4 << 2);
  const int aDst = (arow << 6) + ((((ak4 >> 1) ^ (arow & 3)) << 4)) + ((ak4 & 1) << 3);

  // ---------- B staging: 6 slots/thread, pre-swizzled source ----------
  const __hip_bfloat16* bP[6];
  int bDst[6];
#pragma unroll
  for (int q = 0; q < 6; ++q) {
    int s   = (q << 9) + tid;
    int row = s >> 2, chk = s & 3;
    bP[q]   = Wb + (size_t)row * DDIM + ((chk ^ (row & 3)) << 3);
    bDst[q] = FABY + (s << 4);
  }

  // ---------- MFMA fragment LDS read offsets (swizzle-matched) ----------
  const int lr = lane & 15, lq = lane >> 4;
  int aRd[4], bRd[6];
#pragma unroll
  for (int i = 0; i < 4; ++i) {
    int row = i * 16 + lr;
    aRd[i] = row * 64 + ((lq ^ (row & 3)) << 4);
  }
#pragma unroll
  for (int j = 0; j < 6; ++j) {
    int row = w * 96 + j * 16 + lr;
    bRd[j] = FABY + row * 64 + ((lq ^ (row & 3)) << 4);
  }

  auto stageB = [&](int t) {
    char* b = smem + (t & 1) * FBUF;
    const int k0 = t << 5;
#pragma unroll
    for (int q = 0; q < 6; ++q) gload16(bP[q] + k0, b + bDst[q]);
  };
  auto putA = [&](int t, float4 ax) {
    const int k = (t << 5) + (ak4 << 2);
    float4 wv = *(const float4*)(lnw_s + k);
    float4 bv = *(const float4*)(lnb_s + k);
    float h0 = silu_f((ax.x - aMean) * aRstd * wv.x + bv.x);
    float h1 = silu_f((ax.y - aMean) * aRstd * wv.y + bv.y);
    float h2 = silu_f((ax.z - aMean) * aRstd * wv.z + bv.z);
    float h3 = silu_f((ax.w - aMean) * aRstd * wv.w + bv.w);
    ushort4 o; o.x = f2bf(h0); o.y = f2bf(h1); o.z = f2bf(h2); o.w = f2bf(h3);
    *(ushort4*)(smem + (t & 1) * FBUF + aDst) = o;
  };

  f32x4 acc[4][6];
#pragma unroll
  for (int i = 0; i < 4; ++i)
#pragma unroll
    for (int j = 0; j < 6; ++j)
      acc[i][j] = (f32x4){0.f, 0.f, 0.f, 0.f};

  // ---------- prologue: stage tile 0 ----------
  {
    float4 ax0 = *(const float4*)(aSrc);
    stageB(0);
    VMW(6);                                  // ax0 landed; B(0) may fly
    putA(0, ax0);
    asm volatile("s_waitcnt lgkmcnt(0)" ::: "memory");
    __builtin_amdgcn_s_barrier();
    asm volatile("" ::: "memory");
  }

  // ---------- main loop: 1 barrier / K-tile, counted vmcnt ----------
  for (int t = 0; t < 32; ++t) {
    float4 axn;
    if (t < 31) {
      axn = *(const float4*)(aSrc + ((t + 1) << 5));
      stageB(t + 1);                         // into buf[(t+1)&1]
    }
    if (t < 31) VMW(7); else VMW(0);         // B(t) landed; 7 newer may fly
    __builtin_amdgcn_sched_barrier(0);

    const char* bb = smem + (t & 1) * FBUF;
    bf16x8 af[4], bfq[6];
#pragma unroll
    for (int i = 0; i < 4; ++i) af[i]  = *(const bf16x8*)(bb + aRd[i]);
#pragma unroll
    for (int j = 0; j < 6; ++j) bfq[j] = *(const bf16x8*)(bb + bRd[j]);

    __builtin_amdgcn_s_setprio(1);
#pragma unroll
    for (int i = 0; i < 4; ++i)
#pragma unroll
      for (int j = 0; j < 6; ++j)
        acc[i][j] = __builtin_amdgcn_mfma_f32_16x16x32_bf16(af[i], bfq[j], acc[i][j], 0, 0, 0);
    __builtin_amdgcn_s_setprio(0);

    if (t < 31) {
      VMW(6);                                // axn landed; B(t+1) may fly
      putA(t + 1, axn);                      // ds_write into buf[(t+1)&1]
    }
    asm volatile("s_waitcnt lgkmcnt(0)" ::: "memory");
    __builtin_amdgcn_s_barrier();
    asm volatile("" ::: "memory");
  }

  // ---------- epilogue: 2 chunks x 32 tokens, full-row f4 stores ----------
  const int b   = m0 >> 10;
  const int hq0 = (m0 & 1023) >> 5;
  float bv[6]; int cj[6], pwj[6], phj[6];
#pragma unroll
  for (int j = 0; j < 6; ++j) {
    int o = w * 96 + j * 16 + lr;            // 0..767
    bv[j]  = bias[o];
    cj[j]  = o % 3;
    int oq = o / 3;
    pwj[j] = oq & 15;
    phj[j] = oq >> 4;                        // 0..15
  }
  float* ldsF = (float*)smem;

#pragma unroll
  for (int g = 0; g < 2; ++g) {
    // write phase: tokens 32g..32g+31, all 768 cols (every wave active)
#pragma unroll
    for (int ii = 0; ii < 2; ++ii) {
      const int i = (g << 1) | ii;
#pragma unroll
      for (int j = 0; j < 6; ++j)
#pragma unroll
        for (int r = 0; r < 4; ++r) {
          const int tk = (ii << 4) | (lq << 2) | r;
          const int f  = (((cj[j] << 4) | phj[j]) << 9) | (tk << 4) | (pwj[j] ^ (lq << 2));
          ldsF[f] = acc[i][j][r] + bv[j];
        }
    }
    __syncthreads();
    // read phase: 6144 f4 in output order -> full 2 KB rows
    const int hh = hq0 + g;
#pragma unroll
    for (int u = 0; u < 12; ++u) {
      const int fl  = ((u << 9) + tid) << 2;
      const int c   = fl >> 13;
      const int ph  = (fl >> 9) & 15;
      const int tk  = (fl >> 4) & 31;
      const int pw0 = fl & 12;
      const int lqw = (tk >> 2) & 3;
      float4 v = *(const float4*)(ldsF + ((fl & ~15) | (pw0 ^ (lqw << 2))));
      const size_t idx = (((size_t)(b * 3 + c)) << 18)
                       + (size_t)((hh << 4) + ph) * 512
                       + (tk << 4) + pw0;
      *(float4*)(out + idx) = v;
    }
    __syncthreads();
  }
}

// ===================== fallback: fused (no workspace) =====================
#define BM 64
#define BK 32
#define NTHR 1024
#define LDS_BYTES 53760

__global__ __launch_bounds__(NTHR, 4)
void fused_kernel(const float* __restrict__ x,
                  const float* __restrict__ lnw,
                  const float* __restrict__ lnb,
                  const float* __restrict__ Wf,
                  const float* __restrict__ bias,
                  float* __restrict__ out)
{
  extern __shared__ char smem[];
  char* AsBase = smem;
  char* BsBase = smem + 4096;
  float* smean = (float*)(smem + 53248);
  float* srstd = smean + BM;

  const int tid = threadIdx.x;
  const int m0  = blockIdx.x * BM;
  const int bb   = m0 >> 10;
  const int h0   = (m0 & 1023) >> 5;

  {
    const int row = tid >> 4;
    const int sub = tid & 15;
    const float4* xr = (const float4*)(x + (size_t)(m0 + row) * DDIM);
    float s = 0.f, ss = 0.f;
#pragma unroll 4
    for (int j = 0; j < 16; ++j) {
      float4 v = xr[sub + (j << 4)];
      s  += v.x + v.y + v.z + v.w;
      ss += v.x * v.x + v.y * v.y + v.z * v.z + v.w * v.w;
    }
#pragma unroll
    for (int off = 1; off < 16; off <<= 1) {
      s  += __shfl_xor(s, off);
      ss += __shfl_xor(ss, off);
    }
    if (sub == 0) {
      float mean = s * (1.f / 1024.f);
      float var  = ss * (1.f / 1024.f) - mean * mean;
      smean[row] = mean;
      srstd[row] = rsqrtf(var + LN_EPS);
    }
  }
  __syncthreads();

  const int arow  = tid >> 4;
  const int acol2 = tid & 15;
  const int aOff  = (m0 + arow) * DDIM + (acol2 << 1);
  const int aDst  = (arow << 6) + ((((acol2 >> 2) ^ ((arow >> 2) & 3)) << 4)) + ((acol2 & 3) << 2);
  const float aMean = smean[arow];
  const float aRstd = srstd[arow];

  int bOffF[6], bDstF[6];
#pragma unroll
  for (int c = 0; c < 6; ++c) {
    int idx = tid + (c << 10);
    int r = idx >> 3, c4 = idx & 7;
    bOffF[c] = r * DDIM + (c4 << 2);
    bDstF[c] = (r << 6) + ((((c4 >> 1) ^ ((r >> 2) & 3)) << 4)) + ((c4 & 1) << 3);
  }

  const int lane = tid & 63;
  const int wid  = tid >> 6;
  const int lr   = lane & 15;
  const int lq   = lane >> 4;
  const int kswz = (lq ^ ((lr >> 2) & 3)) << 4;
  int aRd[4], bRd[3];
#pragma unroll
  for (int i = 0; i < 4; ++i) aRd[i] = (((i << 4) + lr) << 6) + kswz;
#pragma unroll
  for (int j = 0; j < 3; ++j) bRd[j] = ((wid * 48 + (j << 4) + lr) << 6) + kswz;

  float2 aReg, lwReg, lbReg;
  float4 bRegF[6];

  auto loadTile = [&](int tt) {
    const int k0 = tt * BK;
    aReg  = *(const float2*)(x + aOff + k0);
    lwReg = *(const float2*)(lnw + (acol2 << 1) + k0);
    lbReg = *(const float2*)(lnb + (acol2 << 1) + k0);
#pragma unroll
    for (int c = 0; c < 6; ++c)
      bRegF[c] = *(const float4*)(Wf + bOffF[c] + k0);
  };

  auto storeTile = [&]() {
    float hx = (aReg.x - aMean) * aRstd * lwReg.x + lbReg.x;
    float hy = (aReg.y - aMean) * aRstd * lwReg.y + lbReg.y;
    hx = silu_f(hx); hy = silu_f(hy);
    ushort2 ap; ap.x = f2bf(hx); ap.y = f2bf(hy);
    *(ushort2*)(AsBase + aDst) = ap;
#pragma unroll
    for (int c = 0; c < 6; ++c) {
      float4 wv = bRegF[c];
      ushort4 bp; bp.x = f2bf(wv.x); bp.y = f2bf(wv.y); bp.z = f2bf(wv.z); bp.w = f2bf(wv.w);
      *(ushort4*)(BsBase + bDstF[c]) = bp;
    }
  };

  f32x4 acc[4][3];
#pragma unroll
  for (int i = 0; i < 4; ++i)
#pragma unroll
    for (int j = 0; j < 3; ++j)
      acc[i][j] = (f32x4){0.f, 0.f, 0.f, 0.f};

  loadTile(0);
  storeTile();
  __syncthreads();

  for (int t = 0; t < 32; ++t) {
    if (t < 31) loadTile(t + 1);
    bf16x8 af[4], bfr[3];
#pragma unroll
    for (int i = 0; i < 4; ++i) af[i] = *(const bf16x8*)(AsBase + aRd[i]);
#pragma unroll
    for (int j = 0; j < 3; ++j) bfr[j] = *(const bf16x8*)(BsBase + bRd[j]);
#pragma unroll
    for (int i = 0; i < 4; ++i)
#pragma unroll
      for (int j = 0; j < 3; ++j)
        acc[i][j] = __builtin_amdgcn_mfma_f32_16x16x32_bf16(af[i], bfr[j], acc[i][j], 0, 0, 0);
    __syncthreads();
    if (t < 31) storeTile();
    __syncthreads();
  }

  float* ldsF = (float*)smem;
  float bv[3]; int cv[3], phv[3], pwv[3];
#pragma unroll
  for (int j = 0; j < 3; ++j) {
    const int o = wid * 48 + (j << 4) + lr;
    bv[j]  = bias[o];
    cv[j]  = o % 3;
    const int oq = o / 3;
    pwv[j] = oq & 15;
    phv[j] = oq >> 4;
  }

#pragma unroll
  for (int i = 0; i < 4; ++i) {
#pragma unroll
    for (int j = 0; j < 3; ++j) {
#pragma unroll
      for (int r = 0; r < 4; ++r) {
        const int wl  = (lq << 2) + r;
        const int lin = ((cv[j] * 16 + phv[j]) << 8) + (wl << 4) + pwv[j];
        const int dws = lin ^ (cv[j] << 2) ^ (((lin >> 6) & 1) << 4);
        ldsF[dws] = acc[i][j][r] + bv[j];
      }
    }
    __syncthreads();
    const int hq = h0 + (i >> 1);
    const int w0 = (i & 1) << 4;
#pragma unroll
    for (int q = 0; q < 3; ++q) {
      const int g4  = (q << 10) + tid;
      const int dw  = g4 << 2;
      const int run = dw >> 8;
      const int c   = run >> 4;
      const int ph  = run & 15;
      const int wl  = (dw >> 4) & 15;
      const int pw  = dw & 15;
      const int dws = dw ^ (c << 2) ^ (((dw >> 6) & 1) << 4);
      float4 v = *(const float4*)(ldsF + dws);
      const size_t idx = (((size_t)(bb * 3 + c)) << 18)
                       + ((size_t)((hq << 4) + ph) << 9)
                       + ((w0 + wl) << 4) + pw;
      *(float4*)(out + idx) = v;
    }
    __syncthreads();
  }
}

extern "C" void kernel_launch(void* const* d_in, const int* in_sizes, int n_in,
                              void* d_out, int out_size, void* d_ws, size_t ws_size,
                              hipStream_t stream) {
  const float* x    = (const float*)d_in[0];
  const float* lnw  = (const float*)d_in[1];
  const float* lnb  = (const float*)d_in[2];
  const float* W    = (const float*)d_in[3];
  const float* bias = (const float*)d_in[4];
  float* out = (float*)d_out;

  const size_t wbBytes = (size_t)ODIM * DDIM * sizeof(__hip_bfloat16);   // 1.5 MB
  __hip_bfloat16* Wb = (__hip_bfloat16*)d_ws;

  if (ws_size >= wbBytes) {
    wconv_kernel<<<dim3(768), dim3(256), 0, stream>>>((const float4*)W, (ushort4*)Wb,
                                                      ODIM * DDIM / 4);
    fusedln_gemm_kernel<<<dim3(M_TOT / 64), dim3(512), 0, stream>>>(
        x, lnw, lnb, Wb, bias, out);
  } else {
    fused_kernel<<<dim3(M_TOT / BM), dim3(NTHR), LDS_BYTES, stream>>>(
        x, lnw, lnb, W, bias, out);
  }
}

// Round 7
// 112.220 us; speedup vs baseline: 1.2472x; 1.2472x over previous
//
#include <hip/hip_runtime.h>
#include <hip/hip_bf16.h>

#define M_TOT 32768
#define DDIM  1024
#define ODIM  768
#define LN_EPS 1e-5f

typedef __attribute__((__ext_vector_type__(8))) short bf16x8;
typedef __attribute__((__ext_vector_type__(4))) float f32x4;

__device__ __forceinline__ unsigned short f2bf(float f) {
  union { __hip_bfloat16 h; unsigned short u; } cv;
  cv.h = __float2bfloat16(f);
  return cv.u;
}

__device__ __forceinline__ float silu_f(float v) {
  return v / (1.f + __expf(-v));
}

__global__ void wconv_kernel(const float4* __restrict__ Wf, ushort4* __restrict__ Wb, int n4) {
  int i = blockIdx.x * blockDim.x + threadIdx.x;
  if (i >= n4) return;
  float4 v = Wf[i];
  ushort4 o;
  o.x = f2bf(v.x); o.y = f2bf(v.y); o.z = f2bf(v.z); o.w = f2bf(v.w);
  Wb[i] = o;
}

// ===================== kernel 1: LN + SiLU -> h (bf16) =====================
__global__ __launch_bounds__(256)
void ln_silu_kernel(const float* __restrict__ x, const float* __restrict__ lnw,
                    const float* __restrict__ lnb, __hip_bfloat16* __restrict__ h)
{
  const int tid  = threadIdx.x;
  const int lane = tid & 63;
  const int wid  = tid >> 6;
  const int row  = blockIdx.x * 4 + wid;

  const float4* xr = (const float4*)(x + (size_t)row * DDIM);
  float4 v[4];
#pragma unroll
  for (int jj = 0; jj < 4; ++jj) v[jj] = xr[lane + 64 * jj];

  float s = 0.f, ss = 0.f;
#pragma unroll
  for (int jj = 0; jj < 4; ++jj) {
    float4 a = v[jj];
    s  += a.x + a.y + a.z + a.w;
    ss += a.x * a.x + a.y * a.y + a.z * a.z + a.w * a.w;
  }
#pragma unroll
  for (int off = 1; off < 64; off <<= 1) {
    s  += __shfl_xor(s, off);
    ss += __shfl_xor(ss, off);
  }
  const float mean = s * (1.f / 1024.f);
  const float rstd = rsqrtf(ss * (1.f / 1024.f) - mean * mean + LN_EPS);

  ushort4* hr = (ushort4*)(h + (size_t)row * DDIM);
#pragma unroll
  for (int jj = 0; jj < 4; ++jj) {
    float4 wv = ((const float4*)lnw)[lane + 64 * jj];
    float4 bv = ((const float4*)lnb)[lane + 64 * jj];
    float4 a  = v[jj];
    float e0 = silu_f((a.x - mean) * rstd * wv.x + bv.x);
    float e1 = silu_f((a.y - mean) * rstd * wv.y + bv.y);
    float e2 = silu_f((a.z - mean) * rstd * wv.z + bv.z);
    float e3 = silu_f((a.w - mean) * rstd * wv.w + bv.w);
    ushort4 o; o.x = f2bf(e0); o.y = f2bf(e1); o.z = f2bf(e2); o.w = f2bf(e3);
    hr[lane + 64 * jj] = o;
  }
}

// ===================== kernel 2: GEMM + rearrange =====================
// 128x192 tile, BK=32, 256 thr (4 waves as 2Mx2N, each 64x96), 2-phase dbuf
// via global_load_lds with pre-swizzled source.
// Swizzle: chunk ^= (row>>1)&3  -- 64B rows have bank period 2, so the row's
// bits 1-2 (not 0-1) must drive the chunk XOR; (row&3) left rows {r,r+4,r+8,
// r+12} colliding 4-way (measured 7-9M SQ_LDS_BANK_CONFLICT in R3/R5).
#define GBM 128
#define GBN 192
#define ABYTES 8192    // 128 rows x 64 B
#define BBYTES 12288   // 192 rows x 64 B
#define BUFB   20480
#define GLDS   40960

__device__ __forceinline__ void gload16(const void* g, void* l) {
  __builtin_amdgcn_global_load_lds(
      (const __attribute__((address_space(1))) unsigned int*)g,
      (__attribute__((address_space(3))) unsigned int*)l, 16, 0, 0);
}

__global__ __launch_bounds__(256, 3)
void gemm_kernel(const __hip_bfloat16* __restrict__ h,
                 const __hip_bfloat16* __restrict__ Wb,
                 const float* __restrict__ bias,
                 float* __restrict__ out)
{
  extern __shared__ char smem[];
  const int tid  = threadIdx.x;
  const int lane = tid & 63;
  const int w    = tid >> 6;

  // bijective XCD swizzle (1024 % 8 == 0); nt fastest so same-XCD blocks share A
  const int wg = blockIdx.x;
  const int sv = ((wg & 7) << 7) + (wg >> 3);
  const int mt = sv >> 2, nt = sv & 3;
  const int m0 = mt * GBM, n0 = nt * GBN;

  // staging slot precompute: slot -> (row, swizzled source chunk)
  int aRowQ[2], aChkQ[2], bRowQ[3], bChkQ[3];
#pragma unroll
  for (int q = 0; q < 2; ++q) {
    int sA = ((w * 2 + q) << 6) + lane;
    int row = sA >> 2, chk = sA & 3;
    aRowQ[q] = row;
    aChkQ[q] = (chk ^ ((row >> 1) & 3)) << 3;   // element offset of 16B chunk
  }
#pragma unroll
  for (int q = 0; q < 3; ++q) {
    int sB = ((w * 3 + q) << 6) + lane;
    int row = sB >> 2, chk = sB & 3;
    bRowQ[q] = row;
    bChkQ[q] = (chk ^ ((row >> 1) & 3)) << 3;
  }

  // MFMA fragment LDS read offsets (swizzle-matched, conflict-free)
  const int wm = w >> 1, wn = w & 1;
  const int lr = lane & 15, lq = lane >> 4;
  int aRd[4], bRd[6];
#pragma unroll
  for (int i = 0; i < 4; ++i) {
    int row = wm * 64 + i * 16 + lr;
    aRd[i] = row * 64 + ((lq ^ ((row >> 1) & 3)) << 4);
  }
#pragma unroll
  for (int j = 0; j < 6; ++j) {
    int row = wn * 96 + j * 16 + lr;
    bRd[j] = ABYTES + row * 64 + ((lq ^ ((row >> 1) & 3)) << 4);
  }

  auto stage = [&](int buf, int t) {
    const int k0 = t << 5;
    char* base = smem + buf * BUFB;
#pragma unroll
    for (int q = 0; q < 2; ++q)
      gload16(h + (size_t)(m0 + aRowQ[q]) * DDIM + k0 + aChkQ[q],
              base + ((w * 2 + q) << 10));
#pragma unroll
    for (int q = 0; q < 3; ++q)
      gload16(Wb + (size_t)(n0 + bRowQ[q]) * DDIM + k0 + bChkQ[q],
              base + ABYTES + ((w * 3 + q) << 10));
  };

  f32x4 acc[4][6];
#pragma unroll
  for (int i = 0; i < 4; ++i)
#pragma unroll
    for (int j = 0; j < 6; ++j)
      acc[i][j] = (f32x4){0.f, 0.f, 0.f, 0.f};

  stage(0, 0);
  __syncthreads();
  int cur = 0;
  for (int t = 0; t < 32; ++t) {
    if (t < 31) stage(cur ^ 1, t + 1);      // async loads into other buffer
    const char* bb = smem + cur * BUFB;
    bf16x8 af[4], bfq[6];
#pragma unroll
    for (int i = 0; i < 4; ++i) af[i] = *(const bf16x8*)(bb + aRd[i]);
#pragma unroll
    for (int j = 0; j < 6; ++j) bfq[j] = *(const bf16x8*)(bb + bRd[j]);
#pragma unroll
    for (int i = 0; i < 4; ++i)
#pragma unroll
      for (int j = 0; j < 6; ++j)
        acc[i][j] = __builtin_amdgcn_mfma_f32_16x16x32_bf16(af[i], bfq[j], acc[i][j], 0, 0, 0);
    __syncthreads();                        // drains vmcnt; cur free, cur^1 ready
    cur ^= 1;
  }

  // ---------- epilogue: repack 16-token chunks to output order ----------
  const int b   = m0 >> 10;
  const int hl0 = (m0 & 1023) >> 5;
  float bv[6]; int cj[6], pwj[6], phj[6];
#pragma unroll
  for (int j = 0; j < 6; ++j) {
    int o = wn * 96 + j * 16 + lr;
    bv[j]  = bias[n0 + o];
    cj[j]  = o % 3;
    int oq = o / 3;
    pwj[j] = oq & 15;
    phj[j] = oq >> 4;
  }
  float*  ldsF = (float*)smem;
  float4* ldsV = (float4*)smem;
#pragma unroll
  for (int g = 0; g < 8; ++g) {
    if (wm == (g >> 2)) {
      const int i_f = g & 3;
#pragma unroll
      for (int j = 0; j < 6; ++j)
#pragma unroll
        for (int r = 0; r < 4; ++r)
          ldsF[((cj[j] * 4 + phj[j]) << 8) + ((lq * 4 + r) << 4) + pwj[j]] =
              acc[i_f][j][r] + bv[j];
    }
    __syncthreads();
    const int orow_base = ((hl0 + (g >> 1)) << 4) + (nt << 2);
    const int wbase = (g & 1) << 4;
#pragma unroll
    for (int q = 0; q < 3; ++q) {
      int f4  = (q << 8) + tid;
      int run = f4 >> 6;
      int tk  = (f4 >> 2) & 15;
      int pw0 = (f4 & 3) << 2;
      int c   = run >> 2;
      int ph  = run & 3;
      float4 v = ldsV[f4];
      size_t idx = (((size_t)(b * 3 + c)) << 18)
                 + (size_t)(orow_base + ph) * 512
                 + ((wbase + tk) << 4) + pw0;
      *(float4*)(out + idx) = v;
    }
    __syncthreads();
  }
}

// ===================== fallback: fused (no workspace) =====================
#define BM 64
#define BK 32
#define NTHR 1024
#define LDS_BYTES 53760

__global__ __launch_bounds__(NTHR, 4)
void fused_kernel(const float* __restrict__ x,
                  const float* __restrict__ lnw,
                  const float* __restrict__ lnb,
                  const float* __restrict__ Wf,
                  const float* __restrict__ bias,
                  float* __restrict__ out)
{
  extern __shared__ char smem[];
  char* AsBase = smem;
  char* BsBase = smem + 4096;
  float* smean = (float*)(smem + 53248);
  float* srstd = smean + BM;

  const int tid = threadIdx.x;
  const int m0  = blockIdx.x * BM;
  const int bb   = m0 >> 10;
  const int h0   = (m0 & 1023) >> 5;

  {
    const int row = tid >> 4;
    const int sub = tid & 15;
    const float4* xr = (const float4*)(x + (size_t)(m0 + row) * DDIM);
    float s = 0.f, ss = 0.f;
#pragma unroll 4
    for (int j = 0; j < 16; ++j) {
      float4 v = xr[sub + (j << 4)];
      s  += v.x + v.y + v.z + v.w;
      ss += v.x * v.x + v.y * v.y + v.z * v.z + v.w * v.w;
    }
#pragma unroll
    for (int off = 1; off < 16; off <<= 1) {
      s  += __shfl_xor(s, off);
      ss += __shfl_xor(ss, off);
    }
    if (sub == 0) {
      float mean = s * (1.f / 1024.f);
      float var  = ss * (1.f / 1024.f) - mean * mean;
      smean[row] = mean;
      srstd[row] = rsqrtf(var + LN_EPS);
    }
  }
  __syncthreads();

  const int arow  = tid >> 4;
  const int acol2 = tid & 15;
  const int aOff  = (m0 + arow) * DDIM + (acol2 << 1);
  const int aDst  = (arow << 6) + ((((acol2 >> 2) ^ ((arow >> 2) & 3)) << 4)) + ((acol2 & 3) << 2);
  const float aMean = smean[arow];
  const float aRstd = srstd[arow];

  int bOffF[6], bDstF[6];
#pragma unroll
  for (int c = 0; c < 6; ++c) {
    int idx = tid + (c << 10);
    int r = idx >> 3, c4 = idx & 7;
    bOffF[c] = r * DDIM + (c4 << 2);
    bDstF[c] = (r << 6) + ((((c4 >> 1) ^ ((r >> 2) & 3)) << 4)) + ((c4 & 1) << 3);
  }

  const int lane = tid & 63;
  const int wid  = tid >> 6;
  const int lr   = lane & 15;
  const int lq   = lane >> 4;
  const int kswz = (lq ^ ((lr >> 2) & 3)) << 4;
  int aRd[4], bRd[3];
#pragma unroll
  for (int i = 0; i < 4; ++i) aRd[i] = (((i << 4) + lr) << 6) + kswz;
#pragma unroll
  for (int j = 0; j < 3; ++j) bRd[j] = ((wid * 48 + (j << 4) + lr) << 6) + kswz;

  float2 aReg, lwReg, lbReg;
  float4 bRegF[6];

  auto loadTile = [&](int tt) {
    const int k0 = tt * BK;
    aReg  = *(const float2*)(x + aOff + k0);
    lwReg = *(const float2*)(lnw + (acol2 << 1) + k0);
    lbReg = *(const float2*)(lnb + (acol2 << 1) + k0);
#pragma unroll
    for (int c = 0; c < 6; ++c)
      bRegF[c] = *(const float4*)(Wf + bOffF[c] + k0);
  };

  auto storeTile = [&]() {
    float hx = (aReg.x - aMean) * aRstd * lwReg.x + lbReg.x;
    float hy = (aReg.y - aMean) * aRstd * lwReg.y + lbReg.y;
    hx = silu_f(hx); hy = silu_f(hy);
    ushort2 ap; ap.x = f2bf(hx); ap.y = f2bf(hy);
    *(ushort2*)(AsBase + aDst) = ap;
#pragma unroll
    for (int c = 0; c < 6; ++c) {
      float4 wv = bRegF[c];
      ushort4 bp; bp.x = f2bf(wv.x); bp.y = f2bf(wv.y); bp.z = f2bf(wv.z); bp.w = f2bf(wv.w);
      *(ushort4*)(BsBase + bDstF[c]) = bp;
    }
  };

  f32x4 acc[4][3];
#pragma unroll
  for (int i = 0; i < 4; ++i)
#pragma unroll
    for (int j = 0; j < 3; ++j)
      acc[i][j] = (f32x4){0.f, 0.f, 0.f, 0.f};

  loadTile(0);
  storeTile();
  __syncthreads();

  for (int t = 0; t < 32; ++t) {
    if (t < 31) loadTile(t + 1);
    bf16x8 af[4], bfr[3];
#pragma unroll
    for (int i = 0; i < 4; ++i) af[i] = *(const bf16x8*)(AsBase + aRd[i]);
#pragma unroll
    for (int j = 0; j < 3; ++j) bfr[j] = *(const bf16x8*)(BsBase + bRd[j]);
#pragma unroll
    for (int i = 0; i < 4; ++i)
#pragma unroll
      for (int j = 0; j < 3; ++j)
        acc[i][j] = __builtin_amdgcn_mfma_f32_16x16x32_bf16(af[i], bfr[j], acc[i][j], 0, 0, 0);
    __syncthreads();
    if (t < 31) storeTile();
    __syncthreads();
  }

  float* ldsF = (float*)smem;
  float bv[3]; int cv[3], phv[3], pwv[3];
#pragma unroll
  for (int j = 0; j < 3; ++j) {
    const int o = wid * 48 + (j << 4) + lr;
    bv[j]  = bias[o];
    cv[j]  = o % 3;
    const int oq = o / 3;
    pwv[j] = oq & 15;
    phv[j] = oq >> 4;
  }

#pragma unroll
  for (int i = 0; i < 4; ++i) {
#pragma unroll
    for (int j = 0; j < 3; ++j) {
#pragma unroll
      for (int r = 0; r < 4; ++r) {
        const int wl  = (lq << 2) + r;
        const int lin = ((cv[j] * 16 + phv[j]) << 8) + (wl << 4) + pwv[j];
        const int dws = lin ^ (cv[j] << 2) ^ (((lin >> 6) & 1) << 4);
        ldsF[dws] = acc[i][j][r] + bv[j];
      }
    }
    __syncthreads();
    const int hq = h0 + (i >> 1);
    const int w0 = (i & 1) << 4;
#pragma unroll
    for (int q = 0; q < 3; ++q) {
      const int g4  = (q << 10) + tid;
      const int dw  = g4 << 2;
      const int run = dw >> 8;
      const int c   = run >> 4;
      const int ph  = run & 15;
      const int wl  = (dw >> 4) & 15;
      const int pw  = dw & 15;
      const int dws = dw ^ (c << 2) ^ (((dw >> 6) & 1) << 4);
      float4 v = *(const float4*)(ldsF + dws);
      const size_t idx = (((size_t)(bb * 3 + c)) << 18)
                       + ((size_t)((hq << 4) + ph) << 9)
                       + ((w0 + wl) << 4) + pw;
      *(float4*)(out + idx) = v;
    }
    __syncthreads();
  }
}

extern "C" void kernel_launch(void* const* d_in, const int* in_sizes, int n_in,
                              void* d_out, int out_size, void* d_ws, size_t ws_size,
                              hipStream_t stream) {
  const float* x    = (const float*)d_in[0];
  const float* lnw  = (const float*)d_in[1];
  const float* lnb  = (const float*)d_in[2];
  const float* W    = (const float*)d_in[3];
  const float* bias = (const float*)d_in[4];
  float* out = (float*)d_out;

  const size_t wbBytes = (size_t)ODIM * DDIM * sizeof(__hip_bfloat16);   // 1.5 MB
  const size_t hBytes  = (size_t)M_TOT * DDIM * sizeof(__hip_bfloat16);  // 64 MB
  __hip_bfloat16* Wb = (__hip_bfloat16*)d_ws;
  __hip_bfloat16* hb = (__hip_bfloat16*)((char*)d_ws + wbBytes);

  if (ws_size >= wbBytes + hBytes) {
    wconv_kernel<<<dim3(768), dim3(256), 0, stream>>>((const float4*)W, (ushort4*)Wb,
                                                      ODIM * DDIM / 4);
    ln_silu_kernel<<<dim3(M_TOT / 4), dim3(256), 0, stream>>>(x, lnw, lnb, hb);
    gemm_kernel<<<dim3((M_TOT / GBM) * (ODIM / GBN)), dim3(256), GLDS, stream>>>(hb, Wb, bias, out);
  } else {
    fused_kernel<<<dim3(M_TOT / BM), dim3(NTHR), LDS_BYTES, stream>>>(
        x, lnw, lnb, W, bias, out);
  }
}

// Round 8
// 109.046 us; speedup vs baseline: 1.2835x; 1.0291x over previous
//
#include <hip/hip_runtime.h>
#include <hip/hip_bf16.h>

#define M_TOT 32768
#define DDIM  1024
#define ODIM  768
#define LN_EPS 1e-5f

typedef __attribute__((__ext_vector_type__(8))) short bf16x8;
typedef __attribute__((__ext_vector_type__(4))) float f32x4;

__device__ __forceinline__ unsigned short f2bf(float f) {
  union { __hip_bfloat16 h; unsigned short u; } cv;
  cv.h = __float2bfloat16(f);
  return cv.u;
}

__device__ __forceinline__ float silu_f(float v) {
  return v / (1.f + __expf(-v));
}

__global__ void wconv_kernel(const float4* __restrict__ Wf, ushort4* __restrict__ Wb, int n4) {
  int i = blockIdx.x * blockDim.x + threadIdx.x;
  if (i >= n4) return;
  float4 v = Wf[i];
  ushort4 o;
  o.x = f2bf(v.x); o.y = f2bf(v.y); o.z = f2bf(v.z); o.w = f2bf(v.w);
  Wb[i] = o;
}

// ===================== kernel 1: LN + SiLU -> h (bf16) =====================
__global__ __launch_bounds__(256)
void ln_silu_kernel(const float* __restrict__ x, const float* __restrict__ lnw,
                    const float* __restrict__ lnb, __hip_bfloat16* __restrict__ h)
{
  const int tid  = threadIdx.x;
  const int lane = tid & 63;
  const int wid  = tid >> 6;
  const int row  = blockIdx.x * 4 + wid;

  const float4* xr = (const float4*)(x + (size_t)row * DDIM);
  float4 v[4];
#pragma unroll
  for (int jj = 0; jj < 4; ++jj) v[jj] = xr[lane + 64 * jj];

  float s = 0.f, ss = 0.f;
#pragma unroll
  for (int jj = 0; jj < 4; ++jj) {
    float4 a = v[jj];
    s  += a.x + a.y + a.z + a.w;
    ss += a.x * a.x + a.y * a.y + a.z * a.z + a.w * a.w;
  }
#pragma unroll
  for (int off = 1; off < 64; off <<= 1) {
    s  += __shfl_xor(s, off);
    ss += __shfl_xor(ss, off);
  }
  const float mean = s * (1.f / 1024.f);
  const float rstd = rsqrtf(ss * (1.f / 1024.f) - mean * mean + LN_EPS);

  ushort4* hr = (ushort4*)(h + (size_t)row * DDIM);
#pragma unroll
  for (int jj = 0; jj < 4; ++jj) {
    float4 wv = ((const float4*)lnw)[lane + 64 * jj];
    float4 bv = ((const float4*)lnb)[lane + 64 * jj];
    float4 a  = v[jj];
    float e0 = silu_f((a.x - mean) * rstd * wv.x + bv.x);
    float e1 = silu_f((a.y - mean) * rstd * wv.y + bv.y);
    float e2 = silu_f((a.z - mean) * rstd * wv.z + bv.z);
    float e3 = silu_f((a.w - mean) * rstd * wv.w + bv.w);
    ushort4 o; o.x = f2bf(e0); o.y = f2bf(e1); o.z = f2bf(e2); o.w = f2bf(e3);
    hr[lane + 64 * jj] = o;
  }
}

// ============== kernel 2: GEMM + rearrange, ring-4 2-phase counted ==========
// BM=256, BN=192, BK=32; 512 thr = 8 waves (4M x 2N), wave C = 64x96.
// Ring-4 LDS (4 x 28 KB static). Prefetch depth 3; steady wait vmcnt(2L),
// L = 4 (waves 0-3) / 3 (waves 4-7); never drained in steady state.
// Per K-tile: 2 phases {ds_read | stage-part -> barrier -> lgkm(0) ->
// sched_barrier -> setprio(1) 12 MFMA setprio(0) -> barrier}.
// LDS rows = 64 B; swizzle chunk ^= (row>>1)&3 (verified: conflicts 9.2->3.9M).
#define GBM 256
#define GBN 192
#define ABYTES 16384   // 256 rows x 64 B
#define BUFB   28672   // + 192 rows x 64 B

__device__ __forceinline__ void gload16(const void* g, void* l) {
  __builtin_amdgcn_global_load_lds(
      (const __attribute__((address_space(1))) unsigned int*)g,
      (__attribute__((address_space(3))) unsigned int*)l, 16, 0, 0);
}

#define VMW(n) asm volatile("s_waitcnt vmcnt(" #n ")" ::: "memory")

__global__ __launch_bounds__(512, 2)
void gemm_kernel(const __hip_bfloat16* __restrict__ h,
                 const __hip_bfloat16* __restrict__ Wb,
                 const float* __restrict__ bias,
                 float* __restrict__ out)
{
  __shared__ char smem[4 * BUFB];          // 114688 B static
  const int tid  = threadIdx.x;
  const int lane = tid & 63;
  const int w    = tid >> 6;

  // bijective XCD swizzle (512 % 8 == 0); nt fastest -> same-XCD shares A
  const int wg = blockIdx.x;
  const int sv = ((wg & 7) << 6) + (wg >> 3);
  const int mt = sv >> 2, nt = sv & 3;
  const int m0 = mt << 8, n0 = nt * GBN;

  // ---- staging sources (pre-swizzled: 16B chunk ^= (row>>1)&3) ----
  // A: 1024 slots (2/thread); B: 768 slots (2 for tid<256, else 1)
  const __hip_bfloat16* aP[2]; int aD[2];
#pragma unroll
  for (int q = 0; q < 2; ++q) {
    int s = (q << 9) + tid;
    int row = s >> 2, chk = s & 3;
    aP[q] = h + (size_t)(m0 + row) * DDIM + ((chk ^ ((row >> 1) & 3)) << 3);
    aD[q] = s << 4;
  }
  const bool roleB = (tid < 256);          // wave-uniform
  const __hip_bfloat16* bP0; int bD0;
  const __hip_bfloat16* bP1; int bD1;
  {
    int s = tid, row = s >> 2, chk = s & 3;
    bP0 = Wb + (size_t)(n0 + row) * DDIM + ((chk ^ ((row >> 1) & 3)) << 3);
    bD0 = ABYTES + (s << 4);
    int s2 = 512 + (tid & 255);
    int r2 = s2 >> 2, c2 = s2 & 3;
    bP1 = Wb + (size_t)(n0 + r2) * DDIM + ((c2 ^ ((r2 >> 1) & 3)) << 3);
    bD1 = ABYTES + (s2 << 4);
  }

  // ---- MFMA fragment LDS read offsets (swizzle-matched, 2-way max) ----
  const int wm = w >> 1, wn = w & 1;       // 4M x 2N
  const int lr = lane & 15, lq = lane >> 4;
  int aRd[4], bRd[6];
#pragma unroll
  for (int i = 0; i < 4; ++i) {
    int row = wm * 64 + i * 16 + lr;
    aRd[i] = row * 64 + ((lq ^ ((row >> 1) & 3)) << 4);
  }
#pragma unroll
  for (int j = 0; j < 6; ++j) {
    int row = wn * 96 + j * 16 + lr;
    bRd[j] = ABYTES + row * 64 + ((lq ^ ((row >> 1) & 3)) << 4);
  }

  auto stageA = [&](int t) {               // 2 loads/thread
    char* b = smem + (t & 3) * BUFB;
    const int k0 = t << 5;
    gload16(aP[0] + k0, b + aD[0]);
    gload16(aP[1] + k0, b + aD[1]);
  };
  auto stageB = [&](int t) {               // 2 (waves 0-3) / 1 (waves 4-7)
    char* b = smem + (t & 3) * BUFB;
    const int k0 = t << 5;
    gload16(bP0 + k0, b + bD0);
    if (roleB) gload16(bP1 + k0, b + bD1);
  };

  f32x4 acc[4][6];
#pragma unroll
  for (int i = 0; i < 4; ++i)
#pragma unroll
    for (int j = 0; j < 6; ++j)
      acc[i][j] = (f32x4){0.f, 0.f, 0.f, 0.f};

  // prologue: 3 tiles in flight
  stageA(0); stageB(0);
  stageA(1); stageB(1);
  stageA(2); stageB(2);

  for (int t = 0; t < 32; ++t) {
    // wait for stage(t): outstanding may keep stages t+1, t+2 in flight
    if (t <= 29)      { if (roleB) VMW(8); else VMW(6); }
    else if (t == 30) { if (roleB) VMW(4); else VMW(3); }
    else              { VMW(0); }
    __builtin_amdgcn_s_barrier();          // all waves' stage(t) landed
    asm volatile("" ::: "memory");

    const char* bb = smem + (t & 3) * BUFB;
    bf16x8 af[4], bf0[3], bf1[3];

    // ---- phase 0: A frags + B[0..2], stage A-part of t+3, 12 MFMA ----
#pragma unroll
    for (int i = 0; i < 4; ++i) af[i]  = *(const bf16x8*)(bb + aRd[i]);
#pragma unroll
    for (int j = 0; j < 3; ++j) bf0[j] = *(const bf16x8*)(bb + bRd[j]);
    if (t < 29) stageA(t + 3);             // buf (t+3)&3, freed end of iter t-1
    __builtin_amdgcn_s_barrier();
    asm volatile("s_waitcnt lgkmcnt(0)" ::: "memory");
    __builtin_amdgcn_sched_barrier(0);
    __builtin_amdgcn_s_setprio(1);
#pragma unroll
    for (int i = 0; i < 4; ++i)
#pragma unroll
      for (int j = 0; j < 3; ++j)
        acc[i][j] = __builtin_amdgcn_mfma_f32_16x16x32_bf16(af[i], bf0[j], acc[i][j], 0, 0, 0);
    __builtin_amdgcn_s_setprio(0);
    asm volatile("" ::: "memory");
    __builtin_amdgcn_s_barrier();

    // ---- phase 1: B[3..5], stage B-part of t+3, 12 MFMA ----
#pragma unroll
    for (int j = 0; j < 3; ++j) bf1[j] = *(const bf16x8*)(bb + bRd[3 + j]);
    if (t < 29) stageB(t + 3);
    __builtin_amdgcn_s_barrier();
    asm volatile("s_waitcnt lgkmcnt(0)" ::: "memory");
    __builtin_amdgcn_sched_barrier(0);
    __builtin_amdgcn_s_setprio(1);
#pragma unroll
    for (int i = 0; i < 4; ++i)
#pragma unroll
      for (int j = 0; j < 3; ++j)
        acc[i][3 + j] = __builtin_amdgcn_mfma_f32_16x16x32_bf16(af[i], bf1[j], acc[i][3 + j], 0, 0, 0);
    __builtin_amdgcn_s_setprio(0);
    asm volatile("" ::: "memory");
    __builtin_amdgcn_s_barrier();          // buf (t&3) free for stage(t+4)
  }

  // ---------- epilogue: 16 chunks of 16 tokens, coalesced f4 stores ----------
  // chunk buffer [c(3)][pr(4)][tk(16)][pw(16)] f32 = 12 KB; writer spreads
  // banks via pw ^ (lq<<2); reader undoes with lqw = tk>>2.
  const int b   = m0 >> 10;
  const int hl0 = (m0 & 1023) >> 5;
  float bv[6]; int cj[6], pwj[6], prj[6];
#pragma unroll
  for (int j = 0; j < 6; ++j) {
    int o = wn * 96 + j * 16 + lr;         // 0..191
    bv[j]  = bias[n0 + o];
    cj[j]  = o % 3;
    int oq = o / 3;
    pwj[j] = oq & 15;
    prj[j] = oq >> 4;                      // 0..3
  }
  float* ldsF = (float*)smem;

#pragma unroll
  for (int g = 0; g < 16; ++g) {
    if (wm == (g >> 2)) {
      const int i_f = g & 3;
#pragma unroll
      for (int j = 0; j < 6; ++j)
#pragma unroll
        for (int r = 0; r < 4; ++r) {
          const int tk = lq * 4 + r;
          ldsF[((cj[j] * 4 + prj[j]) << 8) + (tk << 4) + (pwj[j] ^ (lq << 2))] =
              acc[i_f][j][r] + bv[j];
        }
    }
    __syncthreads();
    const int hh = hl0 + (g >> 1);
#pragma unroll
    for (int u = 0; u < 2; ++u) {
      if (u == 1 && tid >= 256) break;     // 768 f4 total
      const int f   = (u << 9) + tid;
      const int c   = f >> 8;
      const int pr  = (f >> 6) & 3;
      const int tk  = (f >> 2) & 15;
      const int pw0 = (f & 3) << 2;
      const int lqw = tk >> 2;
      float4 v = *(const float4*)(ldsF + (((c * 4 + pr) << 8) + (tk << 4)
                                          + (pw0 ^ (lqw << 2))));
      const size_t idx = (((size_t)(b * 3 + c)) << 18)
                       + (size_t)((hh << 4) + (nt << 2) + pr) * 512
                       + ((g & 1) << 8) + (tk << 4) + pw0;
      *(float4*)(out + idx) = v;
    }
    __syncthreads();
  }
}

// ===================== fallback: fused (no workspace) =====================
#define BM 64
#define BK 32
#define NTHR 1024
#define LDS_BYTES 53760

__global__ __launch_bounds__(NTHR, 4)
void fused_kernel(const float* __restrict__ x,
                  const float* __restrict__ lnw,
                  const float* __restrict__ lnb,
                  const float* __restrict__ Wf,
                  const float* __restrict__ bias,
                  float* __restrict__ out)
{
  extern __shared__ char smem[];
  char* AsBase = smem;
  char* BsBase = smem + 4096;
  float* smean = (float*)(smem + 53248);
  float* srstd = smean + BM;

  const int tid = threadIdx.x;
  const int m0  = blockIdx.x * BM;
  const int bb   = m0 >> 10;
  const int h0   = (m0 & 1023) >> 5;

  {
    const int row = tid >> 4;
    const int sub = tid & 15;
    const float4* xr = (const float4*)(x + (size_t)(m0 + row) * DDIM);
    float s = 0.f, ss = 0.f;
#pragma unroll 4
    for (int j = 0; j < 16; ++j) {
      float4 v = xr[sub + (j << 4)];
      s  += v.x + v.y + v.z + v.w;
      ss += v.x * v.x + v.y * v.y + v.z * v.z + v.w * v.w;
    }
#pragma unroll
    for (int off = 1; off < 16; off <<= 1) {
      s  += __shfl_xor(s, off);
      ss += __shfl_xor(ss, off);
    }
    if (sub == 0) {
      float mean = s * (1.f / 1024.f);
      float var  = ss * (1.f / 1024.f) - mean * mean;
      smean[row] = mean;
      srstd[row] = rsqrtf(var + LN_EPS);
    }
  }
  __syncthreads();

  const int arow  = tid >> 4;
  const int acol2 = tid & 15;
  const int aOff  = (m0 + arow) * DDIM + (acol2 << 1);
  const int aDst  = (arow << 6) + ((((acol2 >> 2) ^ ((arow >> 2) & 3)) << 4)) + ((acol2 & 3) << 2);
  const float aMean = smean[arow];
  const float aRstd = srstd[arow];

  int bOffF[6], bDstF[6];
#pragma unroll
  for (int c = 0; c < 6; ++c) {
    int idx = tid + (c << 10);
    int r = idx >> 3, c4 = idx & 7;
    bOffF[c] = r * DDIM + (c4 << 2);
    bDstF[c] = (r << 6) + ((((c4 >> 1) ^ ((r >> 2) & 3)) << 4)) + ((c4 & 1) << 3);
  }

  const int lane = tid & 63;
  const int wid  = tid >> 6;
  const int lr   = lane & 15;
  const int lq   = lane >> 4;
  const int kswz = (lq ^ ((lr >> 2) & 3)) << 4;
  int aRd[4], bRd[3];
#pragma unroll
  for (int i = 0; i < 4; ++i) aRd[i] = (((i << 4) + lr) << 6) + kswz;
#pragma unroll
  for (int j = 0; j < 3; ++j) bRd[j] = ((wid * 48 + (j << 4) + lr) << 6) + kswz;

  float2 aReg, lwReg, lbReg;
  float4 bRegF[6];

  auto loadTile = [&](int tt) {
    const int k0 = tt * BK;
    aReg  = *(const float2*)(x + aOff + k0);
    lwReg = *(const float2*)(lnw + (acol2 << 1) + k0);
    lbReg = *(const float2*)(lnb + (acol2 << 1) + k0);
#pragma unroll
    for (int c = 0; c < 6; ++c)
      bRegF[c] = *(const float4*)(Wf + bOffF[c] + k0);
  };

  auto storeTile = [&]() {
    float hx = (aReg.x - aMean) * aRstd * lwReg.x + lbReg.x;
    float hy = (aReg.y - aMean) * aRstd * lwReg.y + lbReg.y;
    hx = silu_f(hx); hy = silu_f(hy);
    ushort2 ap; ap.x = f2bf(hx); ap.y = f2bf(hy);
    *(ushort2*)(AsBase + aDst) = ap;
#pragma unroll
    for (int c = 0; c < 6; ++c) {
      float4 wv = bRegF[c];
      ushort4 bp; bp.x = f2bf(wv.x); bp.y = f2bf(wv.y); bp.z = f2bf(wv.z); bp.w = f2bf(wv.w);
      *(ushort4*)(BsBase + bDstF[c]) = bp;
    }
  };

  f32x4 acc[4][3];
#pragma unroll
  for (int i = 0; i < 4; ++i)
#pragma unroll
    for (int j = 0; j < 3; ++j)
      acc[i][j] = (f32x4){0.f, 0.f, 0.f, 0.f};

  loadTile(0);
  storeTile();
  __syncthreads();

  for (int t = 0; t < 32; ++t) {
    if (t < 31) loadTile(t + 1);
    bf16x8 af[4], bfr[3];
#pragma unroll
    for (int i = 0; i < 4; ++i) af[i] = *(const bf16x8*)(AsBase + aRd[i]);
#pragma unroll
    for (int j = 0; j < 3; ++j) bfr[j] = *(const bf16x8*)(BsBase + bRd[j]);
#pragma unroll
    for (int i = 0; i < 4; ++i)
#pragma unroll
      for (int j = 0; j < 3; ++j)
        acc[i][j] = __builtin_amdgcn_mfma_f32_16x16x32_bf16(af[i], bfr[j], acc[i][j], 0, 0, 0);
    __syncthreads();
    if (t < 31) storeTile();
    __syncthreads();
  }

  float* ldsF = (float*)smem;
  float bv[3]; int cv[3], phv[3], pwv[3];
#pragma unroll
  for (int j = 0; j < 3; ++j) {
    const int o = wid * 48 + (j << 4) + lr;
    bv[j]  = bias[o];
    cv[j]  = o % 3;
    const int oq = o / 3;
    pwv[j] = oq & 15;
    phv[j] = oq >> 4;
  }

#pragma unroll
  for (int i = 0; i < 4; ++i) {
#pragma unroll
    for (int j = 0; j < 3; ++j) {
#pragma unroll
      for (int r = 0; r < 4; ++r) {
        const int wl  = (lq << 2) + r;
        const int lin = ((cv[j] * 16 + phv[j]) << 8) + (wl << 4) + pwv[j];
        const int dws = lin ^ (cv[j] << 2) ^ (((lin >> 6) & 1) << 4);
        ldsF[dws] = acc[i][j][r] + bv[j];
      }
    }
    __syncthreads();
    const int hq = h0 + (i >> 1);
    const int w0 = (i & 1) << 4;
#pragma unroll
    for (int q = 0; q < 3; ++q) {
      const int g4  = (q << 10) + tid;
      const int dw  = g4 << 2;
      const int run = dw >> 8;
      const int c   = run >> 4;
      const int ph  = run & 15;
      const int wl  = (dw >> 4) & 15;
      const int pw  = dw & 15;
      const int dws = dw ^ (c << 2) ^ (((dw >> 6) & 1) << 4);
      float4 v = *(const float4*)(ldsF + dws);
      const size_t idx = (((size_t)(bb * 3 + c)) << 18)
                       + ((size_t)((hq << 4) + ph) << 9)
                       + ((w0 + wl) << 4) + pw;
      *(float4*)(out + idx) = v;
    }
    __syncthreads();
  }
}

extern "C" void kernel_launch(void* const* d_in, const int* in_sizes, int n_in,
                              void* d_out, int out_size, void* d_ws, size_t ws_size,
                              hipStream_t stream) {
  const float* x    = (const float*)d_in[0];
  const float* lnw  = (const float*)d_in[1];
  const float* lnb  = (const float*)d_in[2];
  const float* W    = (const float*)d_in[3];
  const float* bias = (const float*)d_in[4];
  float* out = (float*)d_out;

  const size_t wbBytes = (size_t)ODIM * DDIM * sizeof(__hip_bfloat16);   // 1.5 MB
  const size_t hBytes  = (size_t)M_TOT * DDIM * sizeof(__hip_bfloat16);  // 64 MB
  __hip_bfloat16* Wb = (__hip_bfloat16*)d_ws;
  __hip_bfloat16* hb = (__hip_bfloat16*)((char*)d_ws + wbBytes);

  if (ws_size >= wbBytes + hBytes) {
    wconv_kernel<<<dim3(768), dim3(256), 0, stream>>>((const float4*)W, (ushort4*)Wb,
                                                      ODIM * DDIM / 4);
    ln_silu_kernel<<<dim3(M_TOT / 4), dim3(256), 0, stream>>>(x, lnw, lnb, hb);
    gemm_kernel<<<dim3((M_TOT / GBM) * (ODIM / GBN)), dim3(512), 0, stream>>>(hb, Wb, bias, out);
  } else {
    fused_kernel<<<dim3(M_TOT / BM), dim3(NTHR), LDS_BYTES, stream>>>(
        x, lnw, lnb, W, bias, out);
  }
}

// Round 9
// 103.405 us; speedup vs baseline: 1.3535x; 1.0546x over previous
//
#include <hip/hip_runtime.h>
#include <hip/hip_bf16.h>

#define M_TOT 32768
#define DDIM  1024
#define ODIM  768
#define LN_EPS 1e-5f

typedef __attribute__((__ext_vector_type__(8))) short bf16x8;
typedef __attribute__((__ext_vector_type__(4))) float f32x4;

__device__ __forceinline__ unsigned short f2bf(float f) {
  union { __hip_bfloat16 h; unsigned short u; } cv;
  cv.h = __float2bfloat16(f);
  return cv.u;
}

__device__ __forceinline__ float silu_f(float v) {
  return v / (1.f + __expf(-v));
}

__global__ void wconv_kernel(const float4* __restrict__ Wf, ushort4* __restrict__ Wb, int n4) {
  int i = blockIdx.x * blockDim.x + threadIdx.x;
  if (i >= n4) return;
  float4 v = Wf[i];
  ushort4 o;
  o.x = f2bf(v.x); o.y = f2bf(v.y); o.z = f2bf(v.z); o.w = f2bf(v.w);
  Wb[i] = o;
}

// ===================== kernel 1: LN + SiLU -> h (bf16) =====================
__global__ __launch_bounds__(256)
void ln_silu_kernel(const float* __restrict__ x, const float* __restrict__ lnw,
                    const float* __restrict__ lnb, __hip_bfloat16* __restrict__ h)
{
  const int tid  = threadIdx.x;
  const int lane = tid & 63;
  const int wid  = tid >> 6;
  const int row  = blockIdx.x * 4 + wid;

  const float4* xr = (const float4*)(x + (size_t)row * DDIM);
  float4 v[4];
#pragma unroll
  for (int jj = 0; jj < 4; ++jj) v[jj] = xr[lane + 64 * jj];

  float s = 0.f, ss = 0.f;
#pragma unroll
  for (int jj = 0; jj < 4; ++jj) {
    float4 a = v[jj];
    s  += a.x + a.y + a.z + a.w;
    ss += a.x * a.x + a.y * a.y + a.z * a.z + a.w * a.w;
  }
#pragma unroll
  for (int off = 1; off < 64; off <<= 1) {
    s  += __shfl_xor(s, off);
    ss += __shfl_xor(ss, off);
  }
  const float mean = s * (1.f / 1024.f);
  const float rstd = rsqrtf(ss * (1.f / 1024.f) - mean * mean + LN_EPS);

  ushort4* hr = (ushort4*)(h + (size_t)row * DDIM);
#pragma unroll
  for (int jj = 0; jj < 4; ++jj) {
    float4 wv = ((const float4*)lnw)[lane + 64 * jj];
    float4 bv = ((const float4*)lnb)[lane + 64 * jj];
    float4 a  = v[jj];
    float e0 = silu_f((a.x - mean) * rstd * wv.x + bv.x);
    float e1 = silu_f((a.y - mean) * rstd * wv.y + bv.y);
    float e2 = silu_f((a.z - mean) * rstd * wv.z + bv.z);
    float e3 = silu_f((a.w - mean) * rstd * wv.w + bv.w);
    ushort4 o; o.x = f2bf(e0); o.y = f2bf(e1); o.z = f2bf(e2); o.w = f2bf(e3);
    hr[lane + 64 * jj] = o;
  }
}

// ============== kernel 2: GEMM + rearrange, ring-4, 1 barrier/K-tile ========
// BM=256, BN=192, BK=32; 512 thr = 8 waves (4M x 2N), wave C = 64x96.
// Ring-4 LDS (4 x 28 KB static). Prefetch depth 3, counted vmcnt (never 0
// in steady state). ONE barrier per K-tile: after it, waves FREE-RUN
// {ds_read frags -> MFMA} with compiler-emitted per-wave lgkmcnt waits, so
// wave k's MFMAs overlap wave j's LDS service (the R8 mid-phase barriers
// serialized LDS drain and MFMA pipe; removing them is this round's change).
// Buffer-reuse safety: stage(t+3) -> buf[(t-1)&3] is issued after the top
// barrier of iter t; any wave past that barrier already issued its last
// MFMA of iter t-1, whose auto-lgkmcnt guarantees buf[(t-1)] reads retired.
#define GBM 256
#define GBN 192
#define ABYTES 16384   // 256 rows x 64 B
#define BUFB   28672   // + 192 rows x 64 B

__device__ __forceinline__ void gload16(const void* g, void* l) {
  __builtin_amdgcn_global_load_lds(
      (const __attribute__((address_space(1))) unsigned int*)g,
      (__attribute__((address_space(3))) unsigned int*)l, 16, 0, 0);
}

#define VMW(n) asm volatile("s_waitcnt vmcnt(" #n ")" ::: "memory")

__global__ __launch_bounds__(512, 2)
void gemm_kernel(const __hip_bfloat16* __restrict__ h,
                 const __hip_bfloat16* __restrict__ Wb,
                 const float* __restrict__ bias,
                 float* __restrict__ out)
{
  __shared__ char smem[4 * BUFB];          // 114688 B static
  const int tid  = threadIdx.x;
  const int lane = tid & 63;
  const int w    = tid >> 6;

  // bijective XCD swizzle (512 % 8 == 0); nt fastest -> same-XCD shares A
  const int wg = blockIdx.x;
  const int sv = ((wg & 7) << 6) + (wg >> 3);
  const int mt = sv >> 2, nt = sv & 3;
  const int m0 = mt << 8, n0 = nt * GBN;

  // ---- staging sources (pre-swizzled: 16B chunk ^= (row>>1)&3) ----
  const __hip_bfloat16* aP[2]; int aD[2];
#pragma unroll
  for (int q = 0; q < 2; ++q) {
    int s = (q << 9) + tid;
    int row = s >> 2, chk = s & 3;
    aP[q] = h + (size_t)(m0 + row) * DDIM + ((chk ^ ((row >> 1) & 3)) << 3);
    aD[q] = s << 4;
  }
  const bool roleB = (tid < 256);          // wave-uniform
  const __hip_bfloat16* bP0; int bD0;
  const __hip_bfloat16* bP1; int bD1;
  {
    int s = tid, row = s >> 2, chk = s & 3;
    bP0 = Wb + (size_t)(n0 + row) * DDIM + ((chk ^ ((row >> 1) & 3)) << 3);
    bD0 = ABYTES + (s << 4);
    int s2 = 512 + (tid & 255);
    int r2 = s2 >> 2, c2 = s2 & 3;
    bP1 = Wb + (size_t)(n0 + r2) * DDIM + ((c2 ^ ((r2 >> 1) & 3)) << 3);
    bD1 = ABYTES + (s2 << 4);
  }

  // ---- MFMA fragment LDS read offsets (swizzle-matched) ----
  const int wm = w >> 1, wn = w & 1;       // 4M x 2N
  const int lr = lane & 15, lq = lane >> 4;
  int aRd[4], bRd[6];
#pragma unroll
  for (int i = 0; i < 4; ++i) {
    int row = wm * 64 + i * 16 + lr;
    aRd[i] = row * 64 + ((lq ^ ((row >> 1) & 3)) << 4);
  }
#pragma unroll
  for (int j = 0; j < 6; ++j) {
    int row = wn * 96 + j * 16 + lr;
    bRd[j] = ABYTES + row * 64 + ((lq ^ ((row >> 1) & 3)) << 4);
  }

  auto stageA = [&](int t) {               // 2 loads/thread
    char* b = smem + (t & 3) * BUFB;
    const int k0 = t << 5;
    gload16(aP[0] + k0, b + aD[0]);
    gload16(aP[1] + k0, b + aD[1]);
  };
  auto stageB = [&](int t) {               // 2 (waves 0-3) / 1 (waves 4-7)
    char* b = smem + (t & 3) * BUFB;
    const int k0 = t << 5;
    gload16(bP0 + k0, b + bD0);
    if (roleB) gload16(bP1 + k0, b + bD1);
  };

  f32x4 acc[4][6];
#pragma unroll
  for (int i = 0; i < 4; ++i)
#pragma unroll
    for (int j = 0; j < 6; ++j)
      acc[i][j] = (f32x4){0.f, 0.f, 0.f, 0.f};

  // prologue: 3 tiles in flight
  stageA(0); stageB(0);
  stageA(1); stageB(1);
  stageA(2); stageB(2);

  for (int t = 0; t < 32; ++t) {
    // wait for stage(t); stages t+1, t+2 may remain in flight (per role)
    if (t <= 29)      { if (roleB) VMW(8); else VMW(6); }
    else if (t == 30) { if (roleB) VMW(4); else VMW(3); }
    else              { VMW(0); }
    __builtin_amdgcn_s_barrier();          // the ONLY barrier per K-tile
    asm volatile("" ::: "memory");

    const char* bb = smem + (t & 3) * BUFB;
    bf16x8 af[4], bf0[3], bf1[3];
#pragma unroll
    for (int i = 0; i < 4; ++i) af[i]  = *(const bf16x8*)(bb + aRd[i]);
#pragma unroll
    for (int j = 0; j < 3; ++j) bf0[j] = *(const bf16x8*)(bb + bRd[j]);
    if (t < 29) stageA(t + 3);             // buf (t+3)&3 = buf (t-1)&3, freed

    __builtin_amdgcn_s_setprio(1);
#pragma unroll
    for (int i = 0; i < 4; ++i)
#pragma unroll
      for (int j = 0; j < 3; ++j)
        acc[i][j] = __builtin_amdgcn_mfma_f32_16x16x32_bf16(af[i], bf0[j], acc[i][j], 0, 0, 0);
    __builtin_amdgcn_s_setprio(0);

#pragma unroll
    for (int j = 0; j < 3; ++j) bf1[j] = *(const bf16x8*)(bb + bRd[3 + j]);
    if (t < 29) stageB(t + 3);

    __builtin_amdgcn_s_setprio(1);
#pragma unroll
    for (int i = 0; i < 4; ++i)
#pragma unroll
      for (int j = 0; j < 3; ++j)
        acc[i][3 + j] = __builtin_amdgcn_mfma_f32_16x16x32_bf16(af[i], bf1[j], acc[i][3 + j], 0, 0, 0);
    __builtin_amdgcn_s_setprio(0);
  }

  // ---------- epilogue: 16 chunks of 16 tokens, coalesced f4 stores ----------
  const int b   = m0 >> 10;
  const int hl0 = (m0 & 1023) >> 5;
  float bv[6]; int cj[6], pwj[6], prj[6];
#pragma unroll
  for (int j = 0; j < 6; ++j) {
    int o = wn * 96 + j * 16 + lr;         // 0..191
    bv[j]  = bias[n0 + o];
    cj[j]  = o % 3;
    int oq = o / 3;
    pwj[j] = oq & 15;
    prj[j] = oq >> 4;                      // 0..3
  }
  float* ldsF = (float*)smem;

#pragma unroll
  for (int g = 0; g < 16; ++g) {
    if (wm == (g >> 2)) {
      const int i_f = g & 3;
#pragma unroll
      for (int j = 0; j < 6; ++j)
#pragma unroll
        for (int r = 0; r < 4; ++r) {
          const int tk = lq * 4 + r;
          ldsF[((cj[j] * 4 + prj[j]) << 8) + (tk << 4) + (pwj[j] ^ (lq << 2))] =
              acc[i_f][j][r] + bv[j];
        }
    }
    __syncthreads();
    const int hh = hl0 + (g >> 1);
#pragma unroll
    for (int u = 0; u < 2; ++u) {
      if (u == 1 && tid >= 256) break;     // 768 f4 total
      const int f   = (u << 9) + tid;
      const int c   = f >> 8;
      const int pr  = (f >> 6) & 3;
      const int tk  = (f >> 2) & 15;
      const int pw0 = (f & 3) << 2;
      const int lqw = tk >> 2;
      float4 v = *(const float4*)(ldsF + (((c * 4 + pr) << 8) + (tk << 4)
                                          + (pw0 ^ (lqw << 2))));
      const size_t idx = (((size_t)(b * 3 + c)) << 18)
                       + (size_t)((hh << 4) + (nt << 2) + pr) * 512
                       + ((g & 1) << 8) + (tk << 4) + pw0;
      *(float4*)(out + idx) = v;
    }
    __syncthreads();
  }
}

// ===================== fallback: fused (no workspace) =====================
#define BM 64
#define BK 32
#define NTHR 1024
#define LDS_BYTES 53760

__global__ __launch_bounds__(NTHR, 4)
void fused_kernel(const float* __restrict__ x,
                  const float* __restrict__ lnw,
                  const float* __restrict__ lnb,
                  const float* __restrict__ Wf,
                  const float* __restrict__ bias,
                  float* __restrict__ out)
{
  extern __shared__ char smem[];
  char* AsBase = smem;
  char* BsBase = smem + 4096;
  float* smean = (float*)(smem + 53248);
  float* srstd = smean + BM;

  const int tid = threadIdx.x;
  const int m0  = blockIdx.x * BM;
  const int bb   = m0 >> 10;
  const int h0   = (m0 & 1023) >> 5;

  {
    const int row = tid >> 4;
    const int sub = tid & 15;
    const float4* xr = (const float4*)(x + (size_t)(m0 + row) * DDIM);
    float s = 0.f, ss = 0.f;
#pragma unroll 4
    for (int j = 0; j < 16; ++j) {
      float4 v = xr[sub + (j << 4)];
      s  += v.x + v.y + v.z + v.w;
      ss += v.x * v.x + v.y * v.y + v.z * v.z + v.w * v.w;
    }
#pragma unroll
    for (int off = 1; off < 16; off <<= 1) {
      s  += __shfl_xor(s, off);
      ss += __shfl_xor(ss, off);
    }
    if (sub == 0) {
      float mean = s * (1.f / 1024.f);
      float var  = ss * (1.f / 1024.f) - mean * mean;
      smean[row] = mean;
      srstd[row] = rsqrtf(var + LN_EPS);
    }
  }
  __syncthreads();

  const int arow  = tid >> 4;
  const int acol2 = tid & 15;
  const int aOff  = (m0 + arow) * DDIM + (acol2 << 1);
  const int aDst  = (arow << 6) + ((((acol2 >> 2) ^ ((arow >> 2) & 3)) << 4)) + ((acol2 & 3) << 2);
  const float aMean = smean[arow];
  const float aRstd = srstd[arow];

  int bOffF[6], bDstF[6];
#pragma unroll
  for (int c = 0; c < 6; ++c) {
    int idx = tid + (c << 10);
    int r = idx >> 3, c4 = idx & 7;
    bOffF[c] = r * DDIM + (c4 << 2);
    bDstF[c] = (r << 6) + ((((c4 >> 1) ^ ((r >> 2) & 3)) << 4)) + ((c4 & 1) << 3);
  }

  const int lane = tid & 63;
  const int wid  = tid >> 6;
  const int lr   = lane & 15;
  const int lq   = lane >> 4;
  const int kswz = (lq ^ ((lr >> 2) & 3)) << 4;
  int aRd[4], bRd[3];
#pragma unroll
  for (int i = 0; i < 4; ++i) aRd[i] = (((i << 4) + lr) << 6) + kswz;
#pragma unroll
  for (int j = 0; j < 3; ++j) bRd[j] = ((wid * 48 + (j << 4) + lr) << 6) + kswz;

  float2 aReg, lwReg, lbReg;
  float4 bRegF[6];

  auto loadTile = [&](int tt) {
    const int k0 = tt * BK;
    aReg  = *(const float2*)(x + aOff + k0);
    lwReg = *(const float2*)(lnw + (acol2 << 1) + k0);
    lbReg = *(const float2*)(lnb + (acol2 << 1) + k0);
#pragma unroll
    for (int c = 0; c < 6; ++c)
      bRegF[c] = *(const float4*)(Wf + bOffF[c] + k0);
  };

  auto storeTile = [&]() {
    float hx = (aReg.x - aMean) * aRstd * lwReg.x + lbReg.x;
    float hy = (aReg.y - aMean) * aRstd * lwReg.y + lbReg.y;
    hx = silu_f(hx); hy = silu_f(hy);
    ushort2 ap; ap.x = f2bf(hx); ap.y = f2bf(hy);
    *(ushort2*)(AsBase + aDst) = ap;
#pragma unroll
    for (int c = 0; c < 6; ++c) {
      float4 wv = bRegF[c];
      ushort4 bp; bp.x = f2bf(wv.x); bp.y = f2bf(wv.y); bp.z = f2bf(wv.z); bp.w = f2bf(wv.w);
      *(ushort4*)(BsBase + bDstF[c]) = bp;
    }
  };

  f32x4 acc[4][3];
#pragma unroll
  for (int i = 0; i < 4; ++i)
#pragma unroll
    for (int j = 0; j < 3; ++j)
      acc[i][j] = (f32x4){0.f, 0.f, 0.f, 0.f};

  loadTile(0);
  storeTile();
  __syncthreads();

  for (int t = 0; t < 32; ++t) {
    if (t < 31) loadTile(t + 1);
    bf16x8 af[4], bfr[3];
#pragma unroll
    for (int i = 0; i < 4; ++i) af[i] = *(const bf16x8*)(AsBase + aRd[i]);
#pragma unroll
    for (int j = 0; j < 3; ++j) bfr[j] = *(const bf16x8*)(BsBase + bRd[j]);
#pragma unroll
    for (int i = 0; i < 4; ++i)
#pragma unroll
      for (int j = 0; j < 3; ++j)
        acc[i][j] = __builtin_amdgcn_mfma_f32_16x16x32_bf16(af[i], bfr[j], acc[i][j], 0, 0, 0);
    __syncthreads();
    if (t < 31) storeTile();
    __syncthreads();
  }

  float* ldsF = (float*)smem;
  float bv[3]; int cv[3], phv[3], pwv[3];
#pragma unroll
  for (int j = 0; j < 3; ++j) {
    const int o = wid * 48 + (j << 4) + lr;
    bv[j]  = bias[o];
    cv[j]  = o % 3;
    const int oq = o / 3;
    pwv[j] = oq & 15;
    phv[j] = oq >> 4;
  }

#pragma unroll
  for (int i = 0; i < 4; ++i) {
#pragma unroll
    for (int j = 0; j < 3; ++j) {
#pragma unroll
      for (int r = 0; r < 4; ++r) {
        const int wl  = (lq << 2) + r;
        const int lin = ((cv[j] * 16 + phv[j]) << 8) + (wl << 4) + pwv[j];
        const int dws = lin ^ (cv[j] << 2) ^ (((lin >> 6) & 1) << 4);
        ldsF[dws] = acc[i][j][r] + bv[j];
      }
    }
    __syncthreads();
    const int hq = h0 + (i >> 1);
    const int w0 = (i & 1) << 4;
#pragma unroll
    for (int q = 0; q < 3; ++q) {
      const int g4  = (q << 10) + tid;
      const int dw  = g4 << 2;
      const int run = dw >> 8;
      const int c   = run >> 4;
      const int ph  = run & 15;
      const int wl  = (dw >> 4) & 15;
      const int pw  = dw & 15;
      const int dws = dw ^ (c << 2) ^ (((dw >> 6) & 1) << 4);
      float4 v = *(const float4*)(ldsF + dws);
      const size_t idx = (((size_t)(bb * 3 + c)) << 18)
                       + ((size_t)((hq << 4) + ph) << 9)
                       + ((w0 + wl) << 4) + pw;
      *(float4*)(out + idx) = v;
    }
    __syncthreads();
  }
}

extern "C" void kernel_launch(void* const* d_in, const int* in_sizes, int n_in,
                              void* d_out, int out_size, void* d_ws, size_t ws_size,
                              hipStream_t stream) {
  const float* x    = (const float*)d_in[0];
  const float* lnw  = (const float*)d_in[1];
  const float* lnb  = (const float*)d_in[2];
  const float* W    = (const float*)d_in[3];
  const float* bias = (const float*)d_in[4];
  float* out = (float*)d_out;

  const size_t wbBytes = (size_t)ODIM * DDIM * sizeof(__hip_bfloat16);   // 1.5 MB
  const size_t hBytes  = (size_t)M_TOT * DDIM * sizeof(__hip_bfloat16);  // 64 MB
  __hip_bfloat16* Wb = (__hip_bfloat16*)d_ws;
  __hip_bfloat16* hb = (__hip_bfloat16*)((char*)d_ws + wbBytes);

  if (ws_size >= wbBytes + hBytes) {
    wconv_kernel<<<dim3(768), dim3(256), 0, stream>>>((const float4*)W, (ushort4*)Wb,
                                                      ODIM * DDIM / 4);
    ln_silu_kernel<<<dim3(M_TOT / 4), dim3(256), 0, stream>>>(x, lnw, lnb, hb);
    gemm_kernel<<<dim3((M_TOT / GBM) * (ODIM / GBN)), dim3(512), 0, stream>>>(hb, Wb, bias, out);
  } else {
    fused_kernel<<<dim3(M_TOT / BM), dim3(NTHR), LDS_BYTES, stream>>>(
        x, lnw, lnb, W, bias, out);
  }
}